// Round 1
// baseline (168.041 us; speedup 1.0000x reference)
//
#include <hip/hip_runtime.h>
#include <math.h>

// SS2D: B=1, D=96, H=W=96, L=9216, K=4, N=16, R=6, C=38
constexpr int cK = 4, cD = 96, cH = 96, cW = 96, cL = 9216;
constexpr int cN = 16, cR = 6, cC = 38;
constexpr int cCH = 96;   // number of chunks (one per row)
constexpr int cCL = 96;   // chunk length

// workspace layout (float offsets)
constexpr long OFF_DELTA = 0;                          // [K][D][L]
constexpr long OFF_BS    = OFF_DELTA + (long)cK*cD*cL; // [K][L][N]
constexpr long OFF_CS    = OFF_BS    + (long)cK*cL*cN; // [K][L][N]
constexpr long OFF_P     = OFF_CS    + (long)cK*cL*cN; // [K][D][CH][N]
constexpr long OFF_S     = OFF_P     + (long)cK*cD*cCH*cN;
constexpr long OFF_HIN   = OFF_S     + (long)cK*cD*cCH*cN;
constexpr long OFF_Y     = OFF_HIN   + (long)cK*cD*cCH*cN; // [K][D][L]

// xs[k][d][l] = x[d][src(k,l)] with src affine per row-chunk:
// l = r*96 + j  ->  src = a + j*st
__device__ __forceinline__ void src_map(int k, int r, int& a, int& st) {
    if (k == 0)      { a = r * cW;                    st = 1;   }
    else if (k == 1) { a = r;                         st = cW;  }
    else if (k == 2) { a = (cH-1-r)*cW + (cW-1);      st = -1;  }
    else             { a = (cH-1)*cW + (cH-1-r);      st = -cW; }
}

// ---------------- Kernel A: x_dbl projection + delta (softplus) --------------
__global__ __launch_bounds__(256) void kA(const float* __restrict__ x,
                                          const float* __restrict__ xpw,
                                          const float* __restrict__ dtw,
                                          const float* __restrict__ dtb,
                                          float* __restrict__ delta,
                                          float* __restrict__ Bs,
                                          float* __restrict__ Cs) {
    __shared__ float xs[cD][cCL];        // 36 KB
    __shared__ float xdbl[cC][cCL + 1];  // 14.7 KB (pad to break bank conflicts)
    const int r = blockIdx.x;    // row chunk
    const int k = blockIdx.y;
    const int tid = threadIdx.x;
    int a, st; src_map(k, r, a, st);

    for (int e = tid; e < cD * cCL; e += 256) {
        int d = e / cCL, j = e % cCL;
        xs[d][j] = x[d * cL + a + j * st];
    }
    __syncthreads();

    const float* wk = xpw + (long)k * cC * cD;
    for (int o = tid; o < cC * cCL; o += 256) {
        int c = o / cCL, j = o % cCL;
        float s = 0.f;
        #pragma unroll 8
        for (int d = 0; d < cD; ++d) s = fmaf(xs[d][j], wk[c * cD + d], s);
        xdbl[c][j] = s;
    }
    __syncthreads();

    const int l0 = r * cCL;
    // Bs / Cs  -> [k][l][n]
    for (int o = tid; o < cCL * cN; o += 256) {
        int n = o % cN, j = o / cN;
        long idx = ((long)(k * cL + l0 + j)) * cN + n;
        Bs[idx] = xdbl[cR + n][j];
        Cs[idx] = xdbl[cR + cN + n][j];
    }
    // delta = softplus(dts @ dtw + bias) -> [k][d][l]
    for (int o = tid; o < cD * cCL; o += 256) {
        int j = o % cCL, d = o / cCL;
        float s = dtb[k * cD + d];
        #pragma unroll
        for (int rr = 0; rr < cR; ++rr)
            s = fmaf(xdbl[rr][j], dtw[(k * cD + d) * cR + rr], s);
        float sp = fmaxf(s, 0.f) + log1pf(expf(-fabsf(s)));
        delta[((long)(k * cD + d)) * cL + l0 + j] = sp;
    }
}

// -------- Kernel B: phase-1 chunk summaries (P = prod dA, S = local state) ---
__global__ __launch_bounds__(256) void kB(const float* __restrict__ x,
                                          const float* __restrict__ delta,
                                          const float* __restrict__ Bs,
                                          const float* __restrict__ Alog,
                                          float* __restrict__ P,
                                          float* __restrict__ S) {
    const int t = blockIdx.x * 256 + threadIdx.x;
    const int n  = t & 15;
    const int g  = t >> 4;
    const int ch = g % cCH;
    const int d  = (g / cCH) % cD;
    const int k  = g / (cCH * cD);

    const float A = -__expf(Alog[(k * cD + d) * cN + n]);
    const float* dptr = delta + ((long)(k * cD + d)) * cL + ch * cCL;
    const float* bptr = Bs + ((long)(k * cL + ch * cCL)) * cN + n;
    int a, st; src_map(k, ch, a, st);
    const float* xrow = x + (long)d * cL + a;

    float p = 1.f, s = 0.f;
    for (int j = 0; j < cCL; ++j) {
        float dl = dptr[j];
        float bv = bptr[(long)j * cN];
        float xv = xrow[j * st];
        float dA = __expf(dl * A);
        s = fmaf(dA, s, dl * bv * xv);
        p *= dA;
    }
    long o = (((long)(k * cD + d)) * cCH + ch) * cN + n;
    P[o] = p; S[o] = s;
}

// -------- Kernel C: inter-chunk sequential scan -> incoming state per chunk --
__global__ __launch_bounds__(256) void kC(const float* __restrict__ P,
                                          const float* __restrict__ S,
                                          float* __restrict__ hin) {
    const int t = blockIdx.x * 256 + threadIdx.x;  // K*D*N = 6144 threads
    const int n = t & 15;
    const int d = (t >> 4) % cD;
    const int k = t / (16 * cD);
    float h = 0.f;
    long base = ((long)(k * cD + d)) * cCH * cN + n;
    for (int c = 0; c < cCH; ++c) {
        long o = base + (long)c * cN;
        hin[o] = h;
        h = fmaf(P[o], h, S[o]);
    }
}

// -------- Kernel D: phase-3 replay with correct init; y = sum_n h*C + x*Ds ---
__global__ __launch_bounds__(256) void kD(const float* __restrict__ x,
                                          const float* __restrict__ delta,
                                          const float* __restrict__ Bs,
                                          const float* __restrict__ Cs,
                                          const float* __restrict__ Alog,
                                          const float* __restrict__ Dsv,
                                          const float* __restrict__ hin,
                                          float* __restrict__ y) {
    const int t = blockIdx.x * 256 + threadIdx.x;
    const int n  = t & 15;
    const int g  = t >> 4;
    const int ch = g % cCH;
    const int d  = (g / cCH) % cD;
    const int k  = g / (cCH * cD);

    const float A  = -__expf(Alog[(k * cD + d) * cN + n]);
    const float Dv = Dsv[k * cD + d];
    const float* dptr = delta + ((long)(k * cD + d)) * cL + ch * cCL;
    const float* bptr = Bs + ((long)(k * cL + ch * cCL)) * cN + n;
    const float* cptr = Cs + ((long)(k * cL + ch * cCL)) * cN + n;
    int a, st; src_map(k, ch, a, st);
    const float* xrow = x + (long)d * cL + a;
    float* ydst = y + ((long)(k * cD + d)) * cL + ch * cCL;

    float h = hin[(((long)(k * cD + d)) * cCH + ch) * cN + n];
    float yhold = 0.f;
    for (int j = 0; j < cCL; ++j) {
        float dl = dptr[j];
        float bv = bptr[(long)j * cN];
        float cv = cptr[(long)j * cN];
        float xv = xrow[j * st];
        float dA = __expf(dl * A);
        h = fmaf(dA, h, dl * bv * xv);
        float p = h * cv;
        p += __shfl_xor(p, 1, 16);
        p += __shfl_xor(p, 2, 16);
        p += __shfl_xor(p, 4, 16);
        p += __shfl_xor(p, 8, 16);
        float yl = fmaf(Dv, xv, p);
        if ((j & 15) == n) yhold = yl;
        if ((j & 15) == 15) ydst[(j & ~15) + n] = yhold;  // coalesced 64B/group
    }
}

// -------- Kernel E: 4-direction combine + LayerNorm over D ------------------
__global__ __launch_bounds__(256) void kE(const float* __restrict__ y,
                                          const float* __restrict__ lnw,
                                          const float* __restrict__ lnb,
                                          float* __restrict__ out) {
    const int wave = threadIdx.x >> 6;
    const int lane = threadIdx.x & 63;
    const int l = blockIdx.x * 4 + wave;
    const int hp = l / cW, wp = l % cW;
    const int lT = wp * cH + hp;
    const int lr = cL - 1 - l, lTr = cL - 1 - lT;

    float v0, v1 = 0.f, s = 0.f, s2 = 0.f;
    {
        int d = lane;
        v0 = y[((long)(0 * cD + d)) * cL + l]
           + y[((long)(2 * cD + d)) * cL + lr]
           + y[((long)(1 * cD + d)) * cL + lT]
           + y[((long)(3 * cD + d)) * cL + lTr];
        s += v0; s2 += v0 * v0;
    }
    if (lane < 32) {
        int d = lane + 64;
        v1 = y[((long)(0 * cD + d)) * cL + l]
           + y[((long)(2 * cD + d)) * cL + lr]
           + y[((long)(1 * cD + d)) * cL + lT]
           + y[((long)(3 * cD + d)) * cL + lTr];
        s += v1; s2 += v1 * v1;
    }
    #pragma unroll
    for (int m = 32; m >= 1; m >>= 1) {
        s  += __shfl_xor(s,  m, 64);
        s2 += __shfl_xor(s2, m, 64);
    }
    const float mu = s * (1.f / 96.f);
    float var = s2 * (1.f / 96.f) - mu * mu;
    const float rstd = rsqrtf(var + 1e-5f);
    out[(long)l * cD + lane] = (v0 - mu) * rstd * lnw[lane] + lnb[lane];
    if (lane < 32)
        out[(long)l * cD + 64 + lane] = (v1 - mu) * rstd * lnw[64 + lane] + lnb[64 + lane];
}

extern "C" void kernel_launch(void* const* d_in, const int* in_sizes, int n_in,
                              void* d_out, int out_size, void* d_ws, size_t ws_size,
                              hipStream_t stream) {
    const float* x    = (const float*)d_in[0];
    const float* xpw  = (const float*)d_in[1];
    const float* dtw  = (const float*)d_in[2];
    const float* dtb  = (const float*)d_in[3];
    const float* Alog = (const float*)d_in[4];
    const float* Dsv  = (const float*)d_in[5];
    const float* lnw  = (const float*)d_in[6];
    const float* lnb  = (const float*)d_in[7];
    float* ws = (float*)d_ws;

    float* delta = ws + OFF_DELTA;
    float* Bs    = ws + OFF_BS;
    float* Cs    = ws + OFF_CS;
    float* P     = ws + OFF_P;
    float* S     = ws + OFF_S;
    float* hin   = ws + OFF_HIN;
    float* y     = ws + OFF_Y;
    float* out   = (float*)d_out;

    kA<<<dim3(cCH, cK), 256, 0, stream>>>(x, xpw, dtw, dtb, delta, Bs, Cs);
    kB<<<(cK * cD * cCH * cN) / 256, 256, 0, stream>>>(x, delta, Bs, Alog, P, S);
    kC<<<(cK * cD * cN) / 256, 256, 0, stream>>>(P, S, hin);
    kD<<<(cK * cD * cCH * cN) / 256, 256, 0, stream>>>(x, delta, Bs, Cs, Alog, Dsv, hin, y);
    kE<<<cL / 4, 256, 0, stream>>>(y, lnw, lnb, out);
}

// Round 2
// 165.328 us; speedup vs baseline: 1.0164x; 1.0164x over previous
//
#include <hip/hip_runtime.h>
#include <math.h>

// SS2D: B=1, D=96, H=W=96, L=9216, K=4, N=16, R=6, C=38
constexpr int cD = 96, cL = 9216;
constexpr long OFF_XT    = 0;                       // [D][L]  (transposed image)
constexpr long OFF_DELTA = OFF_XT    + (long)cD*cL;          // [K][D][L]
constexpr long OFF_BS    = OFF_DELTA + 4L*cD*cL;             // [K][L][16]
constexpr long OFF_CS    = OFF_BS    + 4L*cL*16;             // [K][L][16]
constexpr long OFF_P     = OFF_CS    + 4L*cL*16;             // [K][D][96][16] (becomes hin)
constexpr long OFF_S     = OFF_P     + 4L*cD*96*16;
constexpr long OFF_Y     = OFF_S     + 4L*cD*96*16;          // [K][L][D]

// ------------ kT: xT[d][w*96+h] = x[d][h*96+w] ------------------------------
__global__ __launch_bounds__(256) void kT(const float* __restrict__ x,
                                          float* __restrict__ xT) {
    __shared__ float t[32][33];
    const int h0 = blockIdx.x * 32, w0 = blockIdx.y * 32, d = blockIdx.z;
    const float* xd = x + (long)d * cL;
    float* xtd = xT + (long)d * cL;
    for (int o = threadIdx.x; o < 1024; o += 256) {
        int i = o >> 5, j = o & 31;
        t[i][j] = xd[(h0 + i) * 96 + w0 + j];
    }
    __syncthreads();
    for (int o = threadIdx.x; o < 1024; o += 256) {
        int i = o >> 5, j = o & 31;
        xtd[(w0 + i) * 96 + h0 + j] = t[j][i];
    }
}

// ------------ kA: G = W_k @ src_k (spatial), fused delta/Bs/Cs --------------
__global__ __launch_bounds__(256) void kA(const float* __restrict__ x,
                                          const float* __restrict__ xT,
                                          const float* __restrict__ xpw,
                                          const float* __restrict__ dtw,
                                          const float* __restrict__ dtb,
                                          float* __restrict__ delta,
                                          float* __restrict__ Bs,
                                          float* __restrict__ Cs) {
    __shared__ float xs[96][64];     // 24 KB
    __shared__ float xd[38][65];     // 9.9 KB
    const int p0 = blockIdx.x * 64;
    const int k  = blockIdx.y;
    const int tid = threadIdx.x;
    const float* src = (k & 1) ? xT : x;

    for (int o = tid; o < 96 * 64; o += 256) {
        int d = o >> 6, pp = o & 63;
        xs[d][pp] = src[(long)d * cL + p0 + pp];
    }
    __syncthreads();

    const int lane = tid & 63;
    const int c0 = __builtin_amdgcn_readfirstlane((tid >> 6) * 10);
    const float* wk = xpw + (long)k * 38 * 96;
    int cidx[10];
    #pragma unroll
    for (int i = 0; i < 10; ++i) { int c = c0 + i; cidx[i] = (c > 37) ? 37 : c; }
    float acc[10];
    #pragma unroll
    for (int i = 0; i < 10; ++i) acc[i] = 0.f;
    #pragma unroll 4
    for (int d = 0; d < 96; ++d) {
        float xv = xs[d][lane];
        #pragma unroll
        for (int i = 0; i < 10; ++i)
            acc[i] = fmaf(xv, wk[cidx[i] * 96 + d], acc[i]);
    }
    #pragma unroll
    for (int i = 0; i < 10; ++i) xd[cidx[i]][lane] = acc[i];
    __syncthreads();

    // Bs/Cs -> [k][p][n]
    for (int o = tid; o < 64 * 16; o += 256) {
        int n = o & 15, pp = o >> 4;
        long idx = ((long)k * cL + p0 + pp) * 16 + n;
        Bs[idx] = xd[6 + n][pp];
        Cs[idx] = xd[22 + n][pp];
    }
    // delta -> [k][d][p]
    for (int o = tid; o < 96 * 64; o += 256) {
        int d = __builtin_amdgcn_readfirstlane(o >> 6);
        int pp = o & 63;
        float s = dtb[k * 96 + d];
        #pragma unroll
        for (int r = 0; r < 6; ++r)
            s = fmaf(xd[r][pp], dtw[(k * 96 + d) * 6 + r], s);
        float sp = fmaxf(s, 0.f) + log1pf(__expf(-fabsf(s)));
        delta[((long)(k * 96 + d)) * cL + p0 + pp] = sp;
    }
}

// ------------ kB: chunk summaries (P = prod dA, S = local state) ------------
__global__ __launch_bounds__(256) void kB(const float* __restrict__ x,
                                          const float* __restrict__ xT,
                                          const float* __restrict__ delta,
                                          const float* __restrict__ Bs,
                                          const float* __restrict__ Alog,
                                          float* __restrict__ P,
                                          float* __restrict__ S) {
    const int t = blockIdx.x * 256 + threadIdx.x;
    const int n = t & 15, g = t >> 4;
    const int d = g % 96, r1 = g / 96;
    const int ch = r1 % 96, k = r1 / 96;

    const float A = -__expf(Alog[(k * 96 + d) * 16 + n]);
    const float* src = (k & 1) ? xT : x;
    const int st = (k < 2) ? 1 : -1;
    int qq = (k < 2) ? ch * 96 : 9215 - ch * 96;
    const float* dp = delta + ((long)(k * 96 + d)) * cL;
    const float* bp = Bs + (long)k * cL * 16 + n;
    const float* xp = src + (long)d * cL;

    float p = 1.f, s = 0.f;
    #pragma unroll 4
    for (int j = 0; j < 96; ++j, qq += st) {
        float dl = dp[qq];
        float bv = bp[(long)qq * 16];
        float xv = xp[qq];
        float dA = __expf(dl * A);
        s = fmaf(dA, s, dl * bv * xv);
        p *= dA;
    }
    long o = (((long)(k * 96 + d)) * 96 + ch) * 16 + n;
    P[o] = p; S[o] = s;
}

// ------------ kC: inter-chunk scan; hin written in place over P -------------
__global__ __launch_bounds__(256) void kC(float* __restrict__ P,
                                          const float* __restrict__ S) {
    const int t = blockIdx.x * 256 + threadIdx.x;   // 6144 threads
    const int n = t & 15, d = (t >> 4) % 96, k = t / (16 * 96);
    float h = 0.f;
    long base = ((long)(k * 96 + d)) * 96 * 16 + n;
    for (int c = 0; c < 96; ++c) {
        long o = base + (long)c * 16;
        float pv = P[o], sv = S[o];
        P[o] = h;                 // hin
        h = fmaf(pv, h, sv);
    }
}

// ------------ kD: replay with init states; y -> [k][q][d] via LDS -----------
__global__ __launch_bounds__(256) void kD(const float* __restrict__ x,
                                          const float* __restrict__ xT,
                                          const float* __restrict__ delta,
                                          const float* __restrict__ Bs,
                                          const float* __restrict__ Cs,
                                          const float* __restrict__ Alog,
                                          const float* __restrict__ Dsv,
                                          const float* __restrict__ hin,
                                          float* __restrict__ y) {
    __shared__ float yl[96][16];    // 6 KB
    const int tid = threadIdx.x;
    const int t = blockIdx.x * 256 + tid;
    const int n = t & 15, g = t >> 4;
    const int d = g % 96, r1 = g / 96;
    const int ch = r1 % 96, k = r1 / 96;
    const int gl = tid >> 4;
    const int dbase = ((blockIdx.x * 16) % 96);

    const float A  = -__expf(Alog[(k * 96 + d) * 16 + n]);
    const float Dv = Dsv[k * 96 + d];
    const float* src = (k & 1) ? xT : x;
    const int st = (k < 2) ? 1 : -1;
    const int qb = (k < 2) ? ch * 96 : 9215 - ch * 96;
    const float* dp = delta + ((long)(k * 96 + d)) * cL;
    const float* bp = Bs + (long)k * cL * 16 + n;
    const float* cp = Cs + (long)k * cL * 16 + n;
    const float* xp = src + (long)d * cL;

    float h = hin[(((long)(k * 96 + d)) * 96 + ch) * 16 + n];
    int qq = qb;
    #pragma unroll 4
    for (int j = 0; j < 96; ++j, qq += st) {
        float dl = dp[qq];
        float bv = bp[(long)qq * 16];
        float cv = cp[(long)qq * 16];
        float xv = xp[qq];
        float dA = __expf(dl * A);
        h = fmaf(dA, h, dl * bv * xv);
        float p = h * cv;
        p += __shfl_xor(p, 1, 16);
        p += __shfl_xor(p, 2, 16);
        p += __shfl_xor(p, 4, 16);
        p += __shfl_xor(p, 8, 16);
        if (n == (j & 15)) yl[j][gl] = fmaf(Dv, xv, p);
    }
    __syncthreads();
    for (int o = tid; o < 96 * 16; o += 256) {
        int j = o >> 4, dg = o & 15;
        int q2 = qb + j * st;
        y[((long)k * cL + q2) * 96 + dbase + dg] = yl[j][dg];
    }
}

// ------------ kE: 4-dir combine + LayerNorm over D --------------------------
__global__ __launch_bounds__(256) void kE(const float* __restrict__ y,
                                          const float* __restrict__ lnw,
                                          const float* __restrict__ lnb,
                                          float* __restrict__ out) {
    const int wave = threadIdx.x >> 6, lane = threadIdx.x & 63;
    const int p = blockIdx.x * 4 + wave;
    const int hh = p / 96, ww = p % 96;
    const int pT = ww * 96 + hh;
    const float* y0 = y;
    const float* y1 = y + 1L * cL * 96;
    const float* y2 = y + 2L * cL * 96;
    const float* y3 = y + 3L * cL * 96;

    float v0, v1 = 0.f, s = 0.f, s2 = 0.f;
    v0 = y0[(long)p * 96 + lane] + y2[(long)p * 96 + lane]
       + y1[(long)pT * 96 + lane] + y3[(long)pT * 96 + lane];
    s += v0; s2 += v0 * v0;
    if (lane < 32) {
        int d2 = lane + 64;
        v1 = y0[(long)p * 96 + d2] + y2[(long)p * 96 + d2]
           + y1[(long)pT * 96 + d2] + y3[(long)pT * 96 + d2];
        s += v1; s2 += v1 * v1;
    }
    #pragma unroll
    for (int m = 32; m >= 1; m >>= 1) {
        s  += __shfl_xor(s,  m, 64);
        s2 += __shfl_xor(s2, m, 64);
    }
    const float mu = s * (1.f / 96.f);
    const float rstd = rsqrtf(s2 * (1.f / 96.f) - mu * mu + 1e-5f);
    out[(long)p * 96 + lane] = (v0 - mu) * rstd * lnw[lane] + lnb[lane];
    if (lane < 32)
        out[(long)p * 96 + 64 + lane] = (v1 - mu) * rstd * lnw[64 + lane] + lnb[64 + lane];
}

extern "C" void kernel_launch(void* const* d_in, const int* in_sizes, int n_in,
                              void* d_out, int out_size, void* d_ws, size_t ws_size,
                              hipStream_t stream) {
    const float* x    = (const float*)d_in[0];
    const float* xpw  = (const float*)d_in[1];
    const float* dtw  = (const float*)d_in[2];
    const float* dtb  = (const float*)d_in[3];
    const float* Alog = (const float*)d_in[4];
    const float* Dsv  = (const float*)d_in[5];
    const float* lnw  = (const float*)d_in[6];
    const float* lnb  = (const float*)d_in[7];
    float* ws = (float*)d_ws;

    float* xT    = ws + OFF_XT;
    float* delta = ws + OFF_DELTA;
    float* Bs    = ws + OFF_BS;
    float* Cs    = ws + OFF_CS;
    float* P     = ws + OFF_P;
    float* S     = ws + OFF_S;
    float* y     = ws + OFF_Y;
    float* out   = (float*)d_out;

    kT<<<dim3(3, 3, 96), 256, 0, stream>>>(x, xT);
    kA<<<dim3(144, 4), 256, 0, stream>>>(x, xT, xpw, dtw, dtb, delta, Bs, Cs);
    kB<<<2304, 256, 0, stream>>>(x, xT, delta, Bs, Alog, P, S);
    kC<<<24, 256, 0, stream>>>(P, S);
    kD<<<2304, 256, 0, stream>>>(x, xT, delta, Bs, Cs, Alog, Dsv, P, y);
    kE<<<2304, 256, 0, stream>>>(y, lnw, lnb, out);
}

// Round 3
// 140.514 us; speedup vs baseline: 1.1959x; 1.1766x over previous
//
#include <hip/hip_runtime.h>
#include <math.h>

// SS2D: B=1, D=96, H=W=96, L=9216, K=4, N=16, R=6
constexpr int cD = 96, cL = 9216, cK = 4;
constexpr int cCH = 384, cCL = 24;      // 384 chunks of 24
constexpr float LOG2E = 1.44269504088896f;

// float offsets in ws  (total ~49.5 MB)
constexpr long OFF_XPD   = 0;                        // [2][L][96] position-major x
constexpr long OFF_DELTA = OFF_XPD   + 2L*cL*96;     // [K][L][96]
constexpr long OFF_BS    = OFF_DELTA + 4L*cL*96;     // [K][L][16]
constexpr long OFF_CS    = OFF_BS    + 4L*cL*16;     // [K][L][16]
constexpr long OFF_P     = OFF_CS    + 4L*cL*16;     // [K][CH][96][16] (-> hin in place)
constexpr long OFF_S     = OFF_P     + 4L*cCH*96*16; // [K][CH][96][16]; y [K][L][96] aliases

// ---- kT: position-major transposes: xpd[0][h*96+w][d], xpd[1][w*96+h][d] ---
__global__ __launch_bounds__(256) void kT(const float* __restrict__ x,
                                          float* __restrict__ xpd) {
    __shared__ float t[96][97];
    const int h0 = blockIdx.x;
    for (int o = threadIdx.x; o < 9216; o += 256) {
        int d = o / 96, w = o % 96;
        t[d][w] = x[(long)d * cL + h0 * 96 + w];
    }
    __syncthreads();
    float* x0 = xpd;
    float* x1 = xpd + (long)cL * 96;
    for (int o = threadIdx.x; o < 9216; o += 256) {
        int d = o % 96, w = o / 96;
        float v = t[d][w];
        x0[((long)(h0 * 96 + w)) * 96 + d] = v;
        x1[((long)(w * 96 + h0)) * 96 + d] = v;
    }
}

// ---- kA: G = W_k @ x (spatial order); delta[k][p][d], Bs/Cs[k][p][16] ------
__global__ __launch_bounds__(256) void kA(const float* __restrict__ xpd,
                                          const float* __restrict__ xpw,
                                          const float* __restrict__ dtw,
                                          const float* __restrict__ dtb,
                                          float* __restrict__ delta,
                                          float* __restrict__ Bs,
                                          float* __restrict__ Cs) {
    __shared__ float xs2[64][97];     // 24.8 KB
    __shared__ float xdbl[38][65];    // 9.9 KB
    __shared__ float dtw_l[96 * 6];
    __shared__ float dtb_l[96];
    const int p0 = blockIdx.x * 64;
    const int k  = blockIdx.y;
    const int tid = threadIdx.x;
    const float* src = xpd + (long)(k & 1) * cL * 96;

    for (int o = tid; o < 64 * 96; o += 256) {
        int pp = o / 96, d = o % 96;
        xs2[pp][d] = src[((long)(p0 + pp)) * 96 + d];
    }
    for (int o = tid; o < 96 * 6; o += 256) dtw_l[o] = dtw[k * 96 * 6 + o];
    if (tid < 96) dtb_l[tid] = dtb[k * 96 + tid];
    __syncthreads();

    const int lane = tid & 63;
    const int c0 = __builtin_amdgcn_readfirstlane((tid >> 6) * 10);
    const float* wk = xpw + (long)k * 38 * 96;
    float acc[10];
    #pragma unroll
    for (int i = 0; i < 10; ++i) acc[i] = 0.f;
    #pragma unroll 4
    for (int d = 0; d < 96; ++d) {
        float xv = xs2[lane][d];
        #pragma unroll
        for (int i = 0; i < 10; ++i) {
            int c = c0 + i; c = c > 37 ? 37 : c;
            acc[i] = fmaf(xv, wk[c * 96 + d], acc[i]);
        }
    }
    #pragma unroll
    for (int i = 0; i < 10; ++i) {
        int c = c0 + i; c = c > 37 ? 37 : c;
        xdbl[c][lane] = acc[i];
    }
    __syncthreads();

    for (int o = tid; o < 64 * 16; o += 256) {
        int n = o & 15, pp = o >> 4;
        long idx = ((long)k * cL + p0 + pp) * 16 + n;
        Bs[idx] = xdbl[6 + n][pp];
        Cs[idx] = xdbl[22 + n][pp];
    }
    for (int o = tid; o < 96 * 64; o += 256) {
        int d = o % 96, pp = o / 96;
        float s = dtb_l[d];
        #pragma unroll
        for (int r = 0; r < 6; ++r) s = fmaf(xdbl[r][pp], dtw_l[d * 6 + r], s);
        float sp = fmaxf(s, 0.f) + __logf(1.f + __expf(-fabsf(s)));
        delta[((long)k * cL + p0 + pp) * 96 + d] = sp;
    }
}

// ---- kB: chunk summaries, 16 n-states per thread, lane = d -----------------
__global__ __launch_bounds__(256) void kB(const float* __restrict__ xpd,
                                          const float* __restrict__ delta,
                                          const float* __restrict__ Bs,
                                          const float* __restrict__ Alog,
                                          float* __restrict__ P,
                                          float* __restrict__ S) {
    const int tid = threadIdx.x;
    const int sub = tid >> 7, d = tid & 127;
    const int dc = d < 96 ? d : 95;
    const int gid = blockIdx.x * 2 + sub;
    const int ch = gid % cCH, k = gid / cCH;
    const int k2 = k & 1, rev = k >> 1;
    const int qb = rev ? (cL - 1 - ch * cCL) : ch * cCL;
    const int st = rev ? -1 : 1;

    float a2[16];
    {
        const float* ap = Alog + ((long)(k * 96 + dc)) * 16;
        #pragma unroll
        for (int n = 0; n < 16; ++n)
            a2[n] = -LOG2E * exp2f(LOG2E * ap[n]);
    }
    float h[16];
    #pragma unroll
    for (int n = 0; n < 16; ++n) h[n] = 0.f;
    float sdl = 0.f;

    const float* dp = delta + ((long)k * cL + qb) * 96 + dc;
    const float* xp = xpd + (long)k2 * cL * 96 + (long)qb * 96 + dc;
    const float4* bp = (const float4*)(Bs + ((long)k * cL + qb) * 16);
    const long dstep = (long)st * 96;
    const int bstep = st * 4;

    for (int j = 0; j < cCL; ++j) {
        float dl = *dp, xv = *xp;
        float4 B0 = bp[0], B1 = bp[1], B2 = bp[2], B3 = bp[3];
        float t = dl * xv;
        sdl += dl;
        const float bb[16] = {B0.x,B0.y,B0.z,B0.w, B1.x,B1.y,B1.z,B1.w,
                              B2.x,B2.y,B2.z,B2.w, B3.x,B3.y,B3.z,B3.w};
        #pragma unroll
        for (int n = 0; n < 16; ++n) {
            float e = exp2f(dl * a2[n]);
            h[n] = fmaf(e, h[n], t * bb[n]);
        }
        dp += dstep; xp += dstep; bp += bstep;
    }
    if (d < 96) {
        long o = (((long)k * cCH + ch) * 96 + d) * 16;
        float4* Pp = (float4*)(P + o);
        float4* Sp = (float4*)(S + o);
        #pragma unroll
        for (int q = 0; q < 4; ++q) {
            Pp[q] = make_float4(exp2f(a2[4*q+0]*sdl), exp2f(a2[4*q+1]*sdl),
                                exp2f(a2[4*q+2]*sdl), exp2f(a2[4*q+3]*sdl));
            Sp[q] = make_float4(h[4*q+0], h[4*q+1], h[4*q+2], h[4*q+3]);
        }
    }
}

// ---- kC: inter-chunk scan; hin overwrites P --------------------------------
__global__ __launch_bounds__(64) void kC(float* __restrict__ P,
                                         const float* __restrict__ S) {
    const int t = blockIdx.x * 64 + threadIdx.x;  // 6144 threads
    const int k = t / 1536, r = t % 1536;
    long base = (long)k * cCH * 1536 + r;
    float h = 0.f;
    for (int c = 0; c < cCH; ++c) {
        long o = base + (long)c * 1536;
        float pv = P[o], sv = S[o];
        P[o] = h;
        h = fmaf(pv, h, sv);
    }
}

// ---- kD: replay with init states; y[k][p][d] (aliases S) -------------------
__global__ __launch_bounds__(256) void kD(const float* __restrict__ xpd,
                                          const float* __restrict__ delta,
                                          const float* __restrict__ Bs,
                                          const float* __restrict__ Cs,
                                          const float* __restrict__ Alog,
                                          const float* __restrict__ Dsv,
                                          const float* __restrict__ hin,
                                          float* __restrict__ y) {
    const int tid = threadIdx.x;
    const int sub = tid >> 7, d = tid & 127;
    const int dc = d < 96 ? d : 95;
    const int gid = blockIdx.x * 2 + sub;
    const int ch = gid % cCH, k = gid / cCH;
    const int k2 = k & 1, rev = k >> 1;
    const int qb = rev ? (cL - 1 - ch * cCL) : ch * cCL;
    const int st = rev ? -1 : 1;

    float a2[16];
    {
        const float* ap = Alog + ((long)(k * 96 + dc)) * 16;
        #pragma unroll
        for (int n = 0; n < 16; ++n)
            a2[n] = -LOG2E * exp2f(LOG2E * ap[n]);
    }
    float h[16];
    {
        const float4* hp = (const float4*)(hin + (((long)k * cCH + ch) * 96 + dc) * 16);
        #pragma unroll
        for (int q = 0; q < 4; ++q) {
            float4 hv = hp[q];
            h[4*q+0] = hv.x; h[4*q+1] = hv.y; h[4*q+2] = hv.z; h[4*q+3] = hv.w;
        }
    }
    const float Dv = Dsv[k * 96 + dc];

    const float* dp = delta + ((long)k * cL + qb) * 96 + dc;
    const float* xp = xpd + (long)k2 * cL * 96 + (long)qb * 96 + dc;
    const float4* bp = (const float4*)(Bs + ((long)k * cL + qb) * 16);
    const float4* cp = (const float4*)(Cs + ((long)k * cL + qb) * 16);
    float* yp = y + ((long)k * cL + qb) * 96 + d;
    const long dstep = (long)st * 96;
    const int bstep = st * 4;

    for (int j = 0; j < cCL; ++j) {
        float dl = *dp, xv = *xp;
        float4 B0 = bp[0], B1 = bp[1], B2 = bp[2], B3 = bp[3];
        float4 C0 = cp[0], C1 = cp[1], C2 = cp[2], C3 = cp[3];
        float t = dl * xv;
        const float bb[16] = {B0.x,B0.y,B0.z,B0.w, B1.x,B1.y,B1.z,B1.w,
                              B2.x,B2.y,B2.z,B2.w, B3.x,B3.y,B3.z,B3.w};
        const float cc[16] = {C0.x,C0.y,C0.z,C0.w, C1.x,C1.y,C1.z,C1.w,
                              C2.x,C2.y,C2.z,C2.w, C3.x,C3.y,C3.z,C3.w};
        float yacc = 0.f;
        #pragma unroll
        for (int n = 0; n < 16; ++n) {
            float e = exp2f(dl * a2[n]);
            h[n] = fmaf(e, h[n], t * bb[n]);
            yacc = fmaf(h[n], cc[n], yacc);
        }
        if (d < 96) *yp = fmaf(Dv, xv, yacc);
        dp += dstep; xp += dstep; bp += bstep; cp += bstep; yp += dstep;
    }
}

// ---- kE: 4-dir combine + LayerNorm over D ----------------------------------
__global__ __launch_bounds__(256) void kE(const float* __restrict__ y,
                                          const float* __restrict__ lnw,
                                          const float* __restrict__ lnb,
                                          float* __restrict__ out) {
    const int wave = threadIdx.x >> 6, lane = threadIdx.x & 63;
    const int p = blockIdx.x * 4 + wave;
    const int hh = p / 96, ww = p % 96;
    const int pT = ww * 96 + hh;
    const float* y0 = y;
    const float* y1 = y + 1L * cL * 96;
    const float* y2 = y + 2L * cL * 96;
    const float* y3 = y + 3L * cL * 96;

    float v0, v1 = 0.f, s = 0.f, s2 = 0.f;
    v0 = y0[(long)p * 96 + lane] + y2[(long)p * 96 + lane]
       + y1[(long)pT * 96 + lane] + y3[(long)pT * 96 + lane];
    s += v0; s2 += v0 * v0;
    if (lane < 32) {
        int d2 = lane + 64;
        v1 = y0[(long)p * 96 + d2] + y2[(long)p * 96 + d2]
           + y1[(long)pT * 96 + d2] + y3[(long)pT * 96 + d2];
        s += v1; s2 += v1 * v1;
    }
    #pragma unroll
    for (int m = 32; m >= 1; m >>= 1) {
        s  += __shfl_xor(s,  m, 64);
        s2 += __shfl_xor(s2, m, 64);
    }
    const float mu = s * (1.f / 96.f);
    const float rstd = rsqrtf(s2 * (1.f / 96.f) - mu * mu + 1e-5f);
    out[(long)p * 96 + lane] = (v0 - mu) * rstd * lnw[lane] + lnb[lane];
    if (lane < 32)
        out[(long)p * 96 + 64 + lane] = (v1 - mu) * rstd * lnw[64 + lane] + lnb[64 + lane];
}

extern "C" void kernel_launch(void* const* d_in, const int* in_sizes, int n_in,
                              void* d_out, int out_size, void* d_ws, size_t ws_size,
                              hipStream_t stream) {
    const float* x    = (const float*)d_in[0];
    const float* xpw  = (const float*)d_in[1];
    const float* dtw  = (const float*)d_in[2];
    const float* dtb  = (const float*)d_in[3];
    const float* Alog = (const float*)d_in[4];
    const float* Dsv  = (const float*)d_in[5];
    const float* lnw  = (const float*)d_in[6];
    const float* lnb  = (const float*)d_in[7];
    float* ws = (float*)d_ws;

    float* xpd   = ws + OFF_XPD;
    float* delta = ws + OFF_DELTA;
    float* Bs    = ws + OFF_BS;
    float* Cs    = ws + OFF_CS;
    float* P     = ws + OFF_P;
    float* S     = ws + OFF_S;
    float* y     = ws + OFF_S;   // aliases S (kD reads only hin=P)
    float* out   = (float*)d_out;

    kT<<<96, 256, 0, stream>>>(x, xpd);
    kA<<<dim3(144, 4), 256, 0, stream>>>(xpd, xpw, dtw, dtb, delta, Bs, Cs);
    kB<<<cK * cCH / 2, 256, 0, stream>>>(xpd, delta, Bs, Alog, P, S);
    kC<<<96, 64, 0, stream>>>(P, S);
    kD<<<cK * cCH / 2, 256, 0, stream>>>(xpd, delta, Bs, Cs, Alog, Dsv, P, y);
    kE<<<cL / 4, 256, 0, stream>>>(y, lnw, lnb, out);
}

// Round 4
// 130.077 us; speedup vs baseline: 1.2919x; 1.0802x over previous
//
#include <hip/hip_runtime.h>
#include <math.h>

// SS2D: B=1, D=96, H=W=96, L=9216, K=4, N=16, R=6
constexpr int cD = 96, cL = 9216, cK = 4;
constexpr int cCH = 768, cCL = 12;      // 768 chunks of 12
constexpr int cSUP = 12, cSUPW = 64;    // 12 supers x 64 chunks
constexpr float LOG2E = 1.44269504088896f;

// float offsets in ws (~64 MB)
constexpr long OFF_XPD   = 0;                         // [2][L][96]
constexpr long OFF_DELTA = OFF_XPD   + 2L*cL*96;      // [K][L][96]
constexpr long OFF_BS    = OFF_DELTA + 4L*cL*96;      // [K][L][16]
constexpr long OFF_CS    = OFF_BS    + 4L*cL*16;      // [K][L][16]
constexpr long OFF_P     = OFF_CS    + 4L*cL*16;      // [K][CH][96][16] -> hin
constexpr long OFF_S     = OFF_P     + 4L*cCH*96*16;  // [K][CH][96][16]; y aliases
constexpr long OFF_SP    = OFF_S     + 4L*cCH*96*16;  // [12][6144]
constexpr long OFF_SS    = OFF_SP    + 12L*6144;      // [12][6144]

// ---- kT: position-major: xpd[0][h*96+w][d], xpd[1][w*96+h][d] --------------
__global__ __launch_bounds__(256) void kT(const float* __restrict__ x,
                                          float* __restrict__ xpd) {
    __shared__ float t[96][97];
    const int h0 = blockIdx.x;
    for (int o = threadIdx.x; o < 9216; o += 256) {
        int d = o / 96, w = o % 96;
        t[d][w] = x[(long)d * cL + h0 * 96 + w];
    }
    __syncthreads();
    float* x0 = xpd;
    float* x1 = xpd + (long)cL * 96;
    for (int o = threadIdx.x; o < 9216; o += 256) {
        int d = o % 96, w = o / 96;
        float v = t[d][w];
        x0[((long)(h0 * 96 + w)) * 96 + d] = v;
        x1[((long)(w * 96 + h0)) * 96 + d] = v;
    }
}

// ---- kA: G = W_k @ x (spatial order); delta[k][p][d], Bs/Cs[k][p][16] ------
__global__ __launch_bounds__(256) void kA(const float* __restrict__ xpd,
                                          const float* __restrict__ xpw,
                                          const float* __restrict__ dtw,
                                          const float* __restrict__ dtb,
                                          float* __restrict__ delta,
                                          float* __restrict__ Bs,
                                          float* __restrict__ Cs) {
    __shared__ float xs2[64][97];
    __shared__ float xdbl[38][65];
    __shared__ float dtw_l[96 * 6];
    __shared__ float dtb_l[96];
    const int p0 = blockIdx.x * 64;
    const int k  = blockIdx.y;
    const int tid = threadIdx.x;
    const float* src = xpd + (long)(k & 1) * cL * 96;

    for (int o = tid; o < 64 * 96; o += 256) {
        int pp = o / 96, d = o % 96;
        xs2[pp][d] = src[((long)(p0 + pp)) * 96 + d];
    }
    for (int o = tid; o < 96 * 6; o += 256) dtw_l[o] = dtw[k * 96 * 6 + o];
    if (tid < 96) dtb_l[tid] = dtb[k * 96 + tid];
    __syncthreads();

    const int lane = tid & 63;
    const int c0 = __builtin_amdgcn_readfirstlane((tid >> 6) * 10);
    const float* wk = xpw + (long)k * 38 * 96;
    float acc[10];
    #pragma unroll
    for (int i = 0; i < 10; ++i) acc[i] = 0.f;
    #pragma unroll 4
    for (int d = 0; d < 96; ++d) {
        float xv = xs2[lane][d];
        #pragma unroll
        for (int i = 0; i < 10; ++i) {
            int c = c0 + i; c = c > 37 ? 37 : c;
            acc[i] = fmaf(xv, wk[c * 96 + d], acc[i]);
        }
    }
    #pragma unroll
    for (int i = 0; i < 10; ++i) {
        int c = c0 + i; c = c > 37 ? 37 : c;
        xdbl[c][lane] = acc[i];
    }
    __syncthreads();

    for (int o = tid; o < 64 * 16; o += 256) {
        int n = o & 15, pp = o >> 4;
        long idx = ((long)k * cL + p0 + pp) * 16 + n;
        Bs[idx] = xdbl[6 + n][pp];
        Cs[idx] = xdbl[22 + n][pp];
    }
    for (int o = tid; o < 96 * 64; o += 256) {
        int d = o % 96, pp = o / 96;
        float s = dtb_l[d];
        #pragma unroll
        for (int r = 0; r < 6; ++r) s = fmaf(xdbl[r][pp], dtw_l[d * 6 + r], s);
        float sp = fmaxf(s, 0.f) + __logf(1.f + __expf(-fabsf(s)));
        delta[((long)k * cL + p0 + pp) * 96 + d] = sp;
    }
}

// ---- kB: chunk summaries; block = 4 chunks x 96 d-lanes --------------------
__global__ __launch_bounds__(384) void kB(const float* __restrict__ xpd,
                                          const float* __restrict__ delta,
                                          const float* __restrict__ Bs,
                                          const float* __restrict__ Alog,
                                          float* __restrict__ P,
                                          float* __restrict__ S) {
    const int tid = threadIdx.x;
    const int sub = tid / 96, d = tid % 96;
    const int gid = blockIdx.x * 4 + sub;
    const int ch = gid % cCH, k = gid / cCH;
    const int k2 = k & 1, rev = k >> 1;
    const int qb = rev ? (cL - 1 - ch * cCL) : ch * cCL;
    const int st = rev ? -1 : 1;

    float a2[16];
    {
        const float4* ap = (const float4*)(Alog + ((long)(k * 96 + d)) * 16);
        #pragma unroll
        for (int q = 0; q < 4; ++q) {
            float4 av = ap[q];
            a2[4*q+0] = -LOG2E * exp2f(LOG2E * av.x);
            a2[4*q+1] = -LOG2E * exp2f(LOG2E * av.y);
            a2[4*q+2] = -LOG2E * exp2f(LOG2E * av.z);
            a2[4*q+3] = -LOG2E * exp2f(LOG2E * av.w);
        }
    }
    float h[16];
    #pragma unroll
    for (int n = 0; n < 16; ++n) h[n] = 0.f;
    float sdl = 0.f;

    const float* dp = delta + ((long)k * cL + qb) * 96 + d;
    const float* xp = xpd + (long)k2 * cL * 96 + (long)qb * 96 + d;
    const float4* bp = (const float4*)(Bs + ((long)k * cL + qb) * 16);
    const long dstep = (long)st * 96;
    const int bstep = st * 4;

    float dl = *dp, xv = *xp;
    float4 B0 = bp[0], B1 = bp[1], B2 = bp[2], B3 = bp[3];
    #pragma unroll
    for (int j = 0; j < cCL; ++j) {
        float ndl = 0.f, nxv = 0.f;
        float4 nB0{}, nB1{}, nB2{}, nB3{};
        if (j + 1 < cCL) {
            dp += dstep; xp += dstep; bp += bstep;
            ndl = *dp; nxv = *xp;
            nB0 = bp[0]; nB1 = bp[1]; nB2 = bp[2]; nB3 = bp[3];
        }
        float t = dl * xv;
        sdl += dl;
        const float bb[16] = {B0.x,B0.y,B0.z,B0.w, B1.x,B1.y,B1.z,B1.w,
                              B2.x,B2.y,B2.z,B2.w, B3.x,B3.y,B3.z,B3.w};
        #pragma unroll
        for (int n = 0; n < 16; ++n) {
            float e = exp2f(dl * a2[n]);
            h[n] = fmaf(e, h[n], t * bb[n]);
        }
        dl = ndl; xv = nxv; B0 = nB0; B1 = nB1; B2 = nB2; B3 = nB3;
    }
    long o = (((long)k * cCH + ch) * 96 + d) * 16;
    float4* Pp = (float4*)(P + o);
    float4* Sp = (float4*)(S + o);
    #pragma unroll
    for (int q = 0; q < 4; ++q) {
        Pp[q] = make_float4(exp2f(a2[4*q+0]*sdl), exp2f(a2[4*q+1]*sdl),
                            exp2f(a2[4*q+2]*sdl), exp2f(a2[4*q+3]*sdl));
        Sp[q] = make_float4(h[4*q+0], h[4*q+1], h[4*q+2], h[4*q+3]);
    }
}

// ---- kC1: super-chunk summaries (64 chunks each) ---------------------------
__global__ __launch_bounds__(256) void kC1(const float* __restrict__ P,
                                           const float* __restrict__ S,
                                           float* __restrict__ SP,
                                           float* __restrict__ SS) {
    const int t = blockIdx.x * 256 + threadIdx.x;    // 73728
    const int seq = t % 6144, sup = t / 6144;
    const int k = seq / 1536, rem = seq % 1536;
    float pr = 1.f, sr = 0.f;
    long base = ((long)k * cCH + sup * cSUPW) * 1536 + rem;
    #pragma unroll 4
    for (int j = 0; j < cSUPW; ++j) {
        long o = base + (long)j * 1536;
        float pv = P[o], sv = S[o];
        sr = fmaf(pv, sr, sv);
        pr *= pv;
    }
    SP[(long)sup * 6144 + seq] = pr;
    SS[(long)sup * 6144 + seq] = sr;
}

// ---- kC2: scan 12 super-summaries (exclusive, in place over SP) ------------
__global__ __launch_bounds__(256) void kC2(float* __restrict__ SP,
                                           const float* __restrict__ SS) {
    const int seq = blockIdx.x * 256 + threadIdx.x;  // 6144
    float h = 0.f;
    #pragma unroll
    for (int s = 0; s < cSUP; ++s) {
        long o = (long)s * 6144 + seq;
        float pv = SP[o], sv = SS[o];
        SP[o] = h;
        h = fmaf(pv, h, sv);
    }
}

// ---- kC3: replay supers; exclusive per-chunk init written over P -----------
__global__ __launch_bounds__(256) void kC3(float* __restrict__ P,
                                           const float* __restrict__ S,
                                           const float* __restrict__ SP) {
    const int t = blockIdx.x * 256 + threadIdx.x;    // 73728
    const int seq = t % 6144, sup = t / 6144;
    const int k = seq / 1536, rem = seq % 1536;
    float h = SP[(long)sup * 6144 + seq];
    long base = ((long)k * cCH + sup * cSUPW) * 1536 + rem;
    #pragma unroll 4
    for (int j = 0; j < cSUPW; ++j) {
        long o = base + (long)j * 1536;
        float pv = P[o], sv = S[o];
        P[o] = h;
        h = fmaf(pv, h, sv);
    }
}

// ---- kD: replay with init states; y[k][p][d] (aliases S) -------------------
__global__ __launch_bounds__(384) void kD(const float* __restrict__ xpd,
                                          const float* __restrict__ delta,
                                          const float* __restrict__ Bs,
                                          const float* __restrict__ Cs,
                                          const float* __restrict__ Alog,
                                          const float* __restrict__ Dsv,
                                          const float* __restrict__ hin,
                                          float* __restrict__ y) {
    const int tid = threadIdx.x;
    const int sub = tid / 96, d = tid % 96;
    const int gid = blockIdx.x * 4 + sub;
    const int ch = gid % cCH, k = gid / cCH;
    const int k2 = k & 1, rev = k >> 1;
    const int qb = rev ? (cL - 1 - ch * cCL) : ch * cCL;
    const int st = rev ? -1 : 1;

    float a2[16];
    {
        const float4* ap = (const float4*)(Alog + ((long)(k * 96 + d)) * 16);
        #pragma unroll
        for (int q = 0; q < 4; ++q) {
            float4 av = ap[q];
            a2[4*q+0] = -LOG2E * exp2f(LOG2E * av.x);
            a2[4*q+1] = -LOG2E * exp2f(LOG2E * av.y);
            a2[4*q+2] = -LOG2E * exp2f(LOG2E * av.z);
            a2[4*q+3] = -LOG2E * exp2f(LOG2E * av.w);
        }
    }
    float h[16];
    {
        const float4* hp = (const float4*)(hin + (((long)k * cCH + ch) * 96 + d) * 16);
        #pragma unroll
        for (int q = 0; q < 4; ++q) {
            float4 hv = hp[q];
            h[4*q+0] = hv.x; h[4*q+1] = hv.y; h[4*q+2] = hv.z; h[4*q+3] = hv.w;
        }
    }
    const float Dv = Dsv[k * 96 + d];

    const float* dp = delta + ((long)k * cL + qb) * 96 + d;
    const float* xp = xpd + (long)k2 * cL * 96 + (long)qb * 96 + d;
    const float4* bp = (const float4*)(Bs + ((long)k * cL + qb) * 16);
    const float4* cp = (const float4*)(Cs + ((long)k * cL + qb) * 16);
    float* yp = y + ((long)k * cL + qb) * 96 + d;
    const long dstep = (long)st * 96;
    const int bstep = st * 4;

    float dl = *dp, xv = *xp;
    float4 B0 = bp[0], B1 = bp[1], B2 = bp[2], B3 = bp[3];
    float4 C0 = cp[0], C1 = cp[1], C2 = cp[2], C3 = cp[3];
    #pragma unroll
    for (int j = 0; j < cCL; ++j) {
        float ndl = 0.f, nxv = 0.f;
        float4 nB0{}, nB1{}, nB2{}, nB3{}, nC0{}, nC1{}, nC2{}, nC3{};
        if (j + 1 < cCL) {
            dp += dstep; xp += dstep; bp += bstep; cp += bstep;
            ndl = *dp; nxv = *xp;
            nB0 = bp[0]; nB1 = bp[1]; nB2 = bp[2]; nB3 = bp[3];
            nC0 = cp[0]; nC1 = cp[1]; nC2 = cp[2]; nC3 = cp[3];
        }
        float t = dl * xv;
        const float bb[16] = {B0.x,B0.y,B0.z,B0.w, B1.x,B1.y,B1.z,B1.w,
                              B2.x,B2.y,B2.z,B2.w, B3.x,B3.y,B3.z,B3.w};
        const float cc[16] = {C0.x,C0.y,C0.z,C0.w, C1.x,C1.y,C1.z,C1.w,
                              C2.x,C2.y,C2.z,C2.w, C3.x,C3.y,C3.z,C3.w};
        float y0 = 0.f, y1 = 0.f, y2 = 0.f, y3 = 0.f;
        #pragma unroll
        for (int q = 0; q < 4; ++q) {
            float e0 = exp2f(dl * a2[4*q+0]);
            float e1 = exp2f(dl * a2[4*q+1]);
            float e2 = exp2f(dl * a2[4*q+2]);
            float e3 = exp2f(dl * a2[4*q+3]);
            h[4*q+0] = fmaf(e0, h[4*q+0], t * bb[4*q+0]);
            h[4*q+1] = fmaf(e1, h[4*q+1], t * bb[4*q+1]);
            h[4*q+2] = fmaf(e2, h[4*q+2], t * bb[4*q+2]);
            h[4*q+3] = fmaf(e3, h[4*q+3], t * bb[4*q+3]);
            if (q == 0) { y0 = h[0]*cc[0]; y1 = h[1]*cc[1]; y2 = h[2]*cc[2]; y3 = h[3]*cc[3]; }
            else {
                y0 = fmaf(h[4*q+0], cc[4*q+0], y0);
                y1 = fmaf(h[4*q+1], cc[4*q+1], y1);
                y2 = fmaf(h[4*q+2], cc[4*q+2], y2);
                y3 = fmaf(h[4*q+3], cc[4*q+3], y3);
            }
        }
        *yp = fmaf(Dv, xv, (y0 + y1) + (y2 + y3));
        yp += dstep;
        dl = ndl; xv = nxv;
        B0 = nB0; B1 = nB1; B2 = nB2; B3 = nB3;
        C0 = nC0; C1 = nC1; C2 = nC2; C3 = nC3;
    }
}

// ---- kE: 4-dir combine + LayerNorm over D ----------------------------------
__global__ __launch_bounds__(256) void kE(const float* __restrict__ y,
                                          const float* __restrict__ lnw,
                                          const float* __restrict__ lnb,
                                          float* __restrict__ out) {
    const int wave = threadIdx.x >> 6, lane = threadIdx.x & 63;
    const int p = blockIdx.x * 4 + wave;
    const int hh = p / 96, ww = p % 96;
    const int pT = ww * 96 + hh;
    const float* y0 = y;
    const float* y1 = y + 1L * cL * 96;
    const float* y2 = y + 2L * cL * 96;
    const float* y3 = y + 3L * cL * 96;

    float v0, v1 = 0.f, s = 0.f, s2 = 0.f;
    v0 = y0[(long)p * 96 + lane] + y2[(long)p * 96 + lane]
       + y1[(long)pT * 96 + lane] + y3[(long)pT * 96 + lane];
    s += v0; s2 += v0 * v0;
    if (lane < 32) {
        int d2 = lane + 64;
        v1 = y0[(long)p * 96 + d2] + y2[(long)p * 96 + d2]
           + y1[(long)pT * 96 + d2] + y3[(long)pT * 96 + d2];
        s += v1; s2 += v1 * v1;
    }
    #pragma unroll
    for (int m = 32; m >= 1; m >>= 1) {
        s  += __shfl_xor(s,  m, 64);
        s2 += __shfl_xor(s2, m, 64);
    }
    const float mu = s * (1.f / 96.f);
    const float rstd = rsqrtf(s2 * (1.f / 96.f) - mu * mu + 1e-5f);
    out[(long)p * 96 + lane] = (v0 - mu) * rstd * lnw[lane] + lnb[lane];
    if (lane < 32)
        out[(long)p * 96 + 64 + lane] = (v1 - mu) * rstd * lnw[64 + lane] + lnb[64 + lane];
}

extern "C" void kernel_launch(void* const* d_in, const int* in_sizes, int n_in,
                              void* d_out, int out_size, void* d_ws, size_t ws_size,
                              hipStream_t stream) {
    const float* x    = (const float*)d_in[0];
    const float* xpw  = (const float*)d_in[1];
    const float* dtw  = (const float*)d_in[2];
    const float* dtb  = (const float*)d_in[3];
    const float* Alog = (const float*)d_in[4];
    const float* Dsv  = (const float*)d_in[5];
    const float* lnw  = (const float*)d_in[6];
    const float* lnb  = (const float*)d_in[7];
    float* ws = (float*)d_ws;

    float* xpd   = ws + OFF_XPD;
    float* delta = ws + OFF_DELTA;
    float* Bs    = ws + OFF_BS;
    float* Cs    = ws + OFF_CS;
    float* P     = ws + OFF_P;     // -> hin after kC3
    float* S     = ws + OFF_S;
    float* SP    = ws + OFF_SP;
    float* SS    = ws + OFF_SS;
    float* y     = ws + OFF_S;     // aliases S (kD reads only hin = P)
    float* out   = (float*)d_out;

    kT<<<96, 256, 0, stream>>>(x, xpd);
    kA<<<dim3(144, 4), 256, 0, stream>>>(xpd, xpw, dtw, dtb, delta, Bs, Cs);
    kB<<<cK * cCH / 4, 384, 0, stream>>>(xpd, delta, Bs, Alog, P, S);
    kC1<<<288, 256, 0, stream>>>(P, S, SP, SS);
    kC2<<<24, 256, 0, stream>>>(SP, SS);
    kC3<<<288, 256, 0, stream>>>(P, S, SP);
    kD<<<cK * cCH / 4, 384, 0, stream>>>(xpd, delta, Bs, Cs, Alog, Dsv, P, y);
    kE<<<cL / 4, 256, 0, stream>>>(y, lnw, lnb, out);
}

// Round 5
// 125.830 us; speedup vs baseline: 1.3355x; 1.0338x over previous
//
#include <hip/hip_runtime.h>
#include <math.h>

// SS2D: B=1, D=96, H=W=96, L=9216, K=4, N=16, R=6
constexpr int cD = 96, cL = 9216, cK = 4;
constexpr int cCH = 768, cCL = 12;      // 768 chunks of 12
constexpr int cSUP = 12, cSUPW = 64;    // 12 supers x 64 chunks
constexpr float LOG2E = 1.44269504088896f;

// float offsets in ws (~64 MB)
constexpr long OFF_XPD   = 0;                         // [2][L][96]
constexpr long OFF_DELTA = OFF_XPD   + 2L*cL*96;      // [K][L][96]
constexpr long OFF_BS    = OFF_DELTA + 4L*cL*96;      // [K][L][16]
constexpr long OFF_CS    = OFF_BS    + 4L*cL*16;      // [K][L][16]
constexpr long OFF_P     = OFF_CS    + 4L*cL*16;      // [K][CH][96][16] -> hin
constexpr long OFF_S     = OFF_P     + 4L*cCH*96*16;  // [K][CH][96][16]; y aliases
constexpr long OFF_SP    = OFF_S     + 4L*cCH*96*16;  // [12][6144]
constexpr long OFF_SS    = OFF_SP    + 12L*6144;      // [12][6144]

__device__ __forceinline__ float4 a2prep(float4 v) {
    return make_float4(-LOG2E * exp2f(LOG2E * v.x), -LOG2E * exp2f(LOG2E * v.y),
                       -LOG2E * exp2f(LOG2E * v.z), -LOG2E * exp2f(LOG2E * v.w));
}
__device__ __forceinline__ float4 hstep(float4 h, float4 a, float dl, float t, float4 B) {
    return make_float4(fmaf(exp2f(dl * a.x), h.x, t * B.x),
                       fmaf(exp2f(dl * a.y), h.y, t * B.y),
                       fmaf(exp2f(dl * a.z), h.z, t * B.z),
                       fmaf(exp2f(dl * a.w), h.w, t * B.w));
}
__device__ __forceinline__ float4 pfin(float4 a, float sdl) {
    return make_float4(exp2f(a.x * sdl), exp2f(a.y * sdl),
                       exp2f(a.z * sdl), exp2f(a.w * sdl));
}
__device__ __forceinline__ float dot4acc(float4 h, float4 c, float acc) {
    return fmaf(h.x, c.x, fmaf(h.y, c.y, fmaf(h.z, c.z, fmaf(h.w, c.w, acc))));
}

// ---- kT: position-major: xpd[0][h*96+w][d], xpd[1][w*96+h][d] --------------
__global__ __launch_bounds__(256) void kT(const float* __restrict__ x,
                                          float* __restrict__ xpd) {
    __shared__ float t[96][97];
    const int h0 = blockIdx.x;
    for (int o = threadIdx.x; o < 9216; o += 256) {
        int d = o / 96, w = o % 96;
        t[d][w] = x[(long)d * cL + h0 * 96 + w];
    }
    __syncthreads();
    float* x0 = xpd;
    float* x1 = xpd + (long)cL * 96;
    for (int o = threadIdx.x; o < 9216; o += 256) {
        int d = o % 96, w = o / 96;
        float v = t[d][w];
        x0[((long)(h0 * 96 + w)) * 96 + d] = v;
        x1[((long)(w * 96 + h0)) * 96 + d] = v;
    }
}

// ---- kA: G = W_k @ x (spatial order); delta[k][p][d], Bs/Cs[k][p][16] ------
__global__ __launch_bounds__(256) void kA(const float* __restrict__ xpd,
                                          const float* __restrict__ xpw,
                                          const float* __restrict__ dtw,
                                          const float* __restrict__ dtb,
                                          float* __restrict__ delta,
                                          float* __restrict__ Bs,
                                          float* __restrict__ Cs) {
    __shared__ float xs2[64][97];
    __shared__ float xdbl[38][65];
    __shared__ float dtw_l[96 * 6];
    __shared__ float dtb_l[96];
    const int p0 = blockIdx.x * 64;
    const int k  = blockIdx.y;
    const int tid = threadIdx.x;
    const float* src = xpd + (long)(k & 1) * cL * 96;

    for (int o = tid; o < 64 * 96; o += 256) {
        int pp = o / 96, d = o % 96;
        xs2[pp][d] = src[((long)(p0 + pp)) * 96 + d];
    }
    for (int o = tid; o < 96 * 6; o += 256) dtw_l[o] = dtw[k * 96 * 6 + o];
    if (tid < 96) dtb_l[tid] = dtb[k * 96 + tid];
    __syncthreads();

    const int lane = tid & 63;
    const int c0 = __builtin_amdgcn_readfirstlane((tid >> 6) * 10);
    const float* wk = xpw + (long)k * 38 * 96;
    float acc[10];
    #pragma unroll
    for (int i = 0; i < 10; ++i) acc[i] = 0.f;
    #pragma unroll 4
    for (int d = 0; d < 96; ++d) {
        float xv = xs2[lane][d];
        #pragma unroll
        for (int i = 0; i < 10; ++i) {
            int c = c0 + i; c = c > 37 ? 37 : c;
            acc[i] = fmaf(xv, wk[c * 96 + d], acc[i]);
        }
    }
    #pragma unroll
    for (int i = 0; i < 10; ++i) {
        int c = c0 + i; c = c > 37 ? 37 : c;
        xdbl[c][lane] = acc[i];
    }
    __syncthreads();

    for (int o = tid; o < 64 * 16; o += 256) {
        int n = o & 15, pp = o >> 4;
        long idx = ((long)k * cL + p0 + pp) * 16 + n;
        Bs[idx] = xdbl[6 + n][pp];
        Cs[idx] = xdbl[22 + n][pp];
    }
    for (int o = tid; o < 96 * 64; o += 256) {
        int d = o % 96, pp = o / 96;
        float s = dtb_l[d];
        #pragma unroll
        for (int r = 0; r < 6; ++r) s = fmaf(xdbl[r][pp], dtw_l[d * 6 + r], s);
        float sp = fmaxf(s, 0.f) + __logf(1.f + __expf(-fabsf(s)));
        delta[((long)k * cL + p0 + pp) * 96 + d] = sp;
    }
}

// ---- kB: chunk summaries; all state in named float4 registers --------------
__global__ __launch_bounds__(384) void kB(const float* __restrict__ xpd,
                                          const float* __restrict__ delta,
                                          const float* __restrict__ Bs,
                                          const float* __restrict__ Alog,
                                          float* __restrict__ P,
                                          float* __restrict__ S) {
    const int tid = threadIdx.x;
    const int sub = tid / 96, d = tid % 96;
    const int gid = blockIdx.x * 4 + sub;
    const int ch = gid % cCH, k = gid / cCH;
    const int k2 = k & 1, rev = k >> 1;
    const int qb = rev ? (cL - 1 - ch * cCL) : ch * cCL;
    const int st = rev ? -1 : 1;

    const float4* ap = (const float4*)(Alog + ((long)(k * 96 + d)) * 16);
    float4 a0 = a2prep(ap[0]), a1 = a2prep(ap[1]);
    float4 a2v = a2prep(ap[2]), a3 = a2prep(ap[3]);
    float4 h0 = make_float4(0.f, 0.f, 0.f, 0.f), h1 = h0, h2 = h0, h3 = h0;
    float sdl = 0.f;

    const float* dp = delta + ((long)k * cL + qb) * 96 + d;
    const float* xp = xpd + (long)k2 * cL * 96 + (long)qb * 96 + d;
    const float4* bp = (const float4*)(Bs + ((long)k * cL + qb) * 16);
    const long dstep = (long)st * 96;
    const int bstep = st * 4;

    #pragma unroll
    for (int j = 0; j < cCL; ++j) {
        float dl = dp[(long)j * dstep];
        float xv = xp[(long)j * dstep];
        float4 B0 = bp[j * bstep + 0], B1 = bp[j * bstep + 1];
        float4 B2 = bp[j * bstep + 2], B3 = bp[j * bstep + 3];
        float t = dl * xv;
        sdl += dl;
        h0 = hstep(h0, a0, dl, t, B0);
        h1 = hstep(h1, a1, dl, t, B1);
        h2 = hstep(h2, a2v, dl, t, B2);
        h3 = hstep(h3, a3, dl, t, B3);
    }
    long o = (((long)k * cCH + ch) * 96 + d) * 16;
    float4* Pp = (float4*)(P + o);
    float4* Sp = (float4*)(S + o);
    Pp[0] = pfin(a0, sdl); Pp[1] = pfin(a1, sdl);
    Pp[2] = pfin(a2v, sdl); Pp[3] = pfin(a3, sdl);
    Sp[0] = h0; Sp[1] = h1; Sp[2] = h2; Sp[3] = h3;
}

// ---- kC1: super-chunk summaries (64 chunks each) ---------------------------
__global__ __launch_bounds__(256) void kC1(const float* __restrict__ P,
                                           const float* __restrict__ S,
                                           float* __restrict__ SP,
                                           float* __restrict__ SS) {
    const int t = blockIdx.x * 256 + threadIdx.x;    // 73728
    const int seq = t % 6144, sup = t / 6144;
    const int k = seq / 1536, rem = seq % 1536;
    float pr = 1.f, sr = 0.f;
    long base = ((long)k * cCH + sup * cSUPW) * 1536 + rem;
    #pragma unroll 4
    for (int j = 0; j < cSUPW; ++j) {
        long o = base + (long)j * 1536;
        float pv = P[o], sv = S[o];
        sr = fmaf(pv, sr, sv);
        pr *= pv;
    }
    SP[(long)sup * 6144 + seq] = pr;
    SS[(long)sup * 6144 + seq] = sr;
}

// ---- kC2: scan 12 super-summaries (exclusive, in place over SP) ------------
__global__ __launch_bounds__(256) void kC2(float* __restrict__ SP,
                                           const float* __restrict__ SS) {
    const int seq = blockIdx.x * 256 + threadIdx.x;  // 6144
    float h = 0.f;
    #pragma unroll
    for (int s = 0; s < cSUP; ++s) {
        long o = (long)s * 6144 + seq;
        float pv = SP[o], sv = SS[o];
        SP[o] = h;
        h = fmaf(pv, h, sv);
    }
}

// ---- kC3: replay supers; exclusive per-chunk init written over P -----------
__global__ __launch_bounds__(256) void kC3(float* __restrict__ P,
                                           const float* __restrict__ S,
                                           const float* __restrict__ SP) {
    const int t = blockIdx.x * 256 + threadIdx.x;    // 73728
    const int seq = t % 6144, sup = t / 6144;
    const int k = seq / 1536, rem = seq % 1536;
    float h = SP[(long)sup * 6144 + seq];
    long base = ((long)k * cCH + sup * cSUPW) * 1536 + rem;
    #pragma unroll 4
    for (int j = 0; j < cSUPW; ++j) {
        long o = base + (long)j * 1536;
        float pv = P[o], sv = S[o];
        P[o] = h;
        h = fmaf(pv, h, sv);
    }
}

// ---- kD: replay with init states; y[k][p][d] (aliases S) -------------------
__global__ __launch_bounds__(384) void kD(const float* __restrict__ xpd,
                                          const float* __restrict__ delta,
                                          const float* __restrict__ Bs,
                                          const float* __restrict__ Cs,
                                          const float* __restrict__ Alog,
                                          const float* __restrict__ Dsv,
                                          const float* __restrict__ hin,
                                          float* __restrict__ y) {
    const int tid = threadIdx.x;
    const int sub = tid / 96, d = tid % 96;
    const int gid = blockIdx.x * 4 + sub;
    const int ch = gid % cCH, k = gid / cCH;
    const int k2 = k & 1, rev = k >> 1;
    const int qb = rev ? (cL - 1 - ch * cCL) : ch * cCL;
    const int st = rev ? -1 : 1;

    const float4* ap = (const float4*)(Alog + ((long)(k * 96 + d)) * 16);
    float4 a0 = a2prep(ap[0]), a1 = a2prep(ap[1]);
    float4 a2v = a2prep(ap[2]), a3 = a2prep(ap[3]);

    const float4* hp = (const float4*)(hin + (((long)k * cCH + ch) * 96 + d) * 16);
    float4 h0 = hp[0], h1 = hp[1], h2 = hp[2], h3 = hp[3];
    const float Dv = Dsv[k * 96 + d];

    const float* dp = delta + ((long)k * cL + qb) * 96 + d;
    const float* xp = xpd + (long)k2 * cL * 96 + (long)qb * 96 + d;
    const float4* bp = (const float4*)(Bs + ((long)k * cL + qb) * 16);
    const float4* cp = (const float4*)(Cs + ((long)k * cL + qb) * 16);
    float* yp = y + ((long)k * cL + qb) * 96 + d;
    const long dstep = (long)st * 96;
    const int bstep = st * 4;

    #pragma unroll
    for (int j = 0; j < cCL; ++j) {
        float dl = dp[(long)j * dstep];
        float xv = xp[(long)j * dstep];
        float4 B0 = bp[j * bstep + 0], B1 = bp[j * bstep + 1];
        float4 B2 = bp[j * bstep + 2], B3 = bp[j * bstep + 3];
        float4 C0 = cp[j * bstep + 0], C1 = cp[j * bstep + 1];
        float4 C2 = cp[j * bstep + 2], C3 = cp[j * bstep + 3];
        float t = dl * xv;
        h0 = hstep(h0, a0, dl, t, B0);
        h1 = hstep(h1, a1, dl, t, B1);
        h2 = hstep(h2, a2v, dl, t, B2);
        h3 = hstep(h3, a3, dl, t, B3);
        float y0 = dot4acc(h0, C0, 0.f);
        float y1 = dot4acc(h1, C1, 0.f);
        float y2 = dot4acc(h2, C2, 0.f);
        float y3 = dot4acc(h3, C3, 0.f);
        yp[(long)j * dstep] = fmaf(Dv, xv, (y0 + y1) + (y2 + y3));
    }
}

// ---- kE: 4-dir combine + LayerNorm over D ----------------------------------
__global__ __launch_bounds__(256) void kE(const float* __restrict__ y,
                                          const float* __restrict__ lnw,
                                          const float* __restrict__ lnb,
                                          float* __restrict__ out) {
    const int wave = threadIdx.x >> 6, lane = threadIdx.x & 63;
    const int p = blockIdx.x * 4 + wave;
    const int hh = p / 96, ww = p % 96;
    const int pT = ww * 96 + hh;
    const float* y0 = y;
    const float* y1 = y + 1L * cL * 96;
    const float* y2 = y + 2L * cL * 96;
    const float* y3 = y + 3L * cL * 96;

    float v0, v1 = 0.f, s = 0.f, s2 = 0.f;
    v0 = y0[(long)p * 96 + lane] + y2[(long)p * 96 + lane]
       + y1[(long)pT * 96 + lane] + y3[(long)pT * 96 + lane];
    s += v0; s2 += v0 * v0;
    if (lane < 32) {
        int d2 = lane + 64;
        v1 = y0[(long)p * 96 + d2] + y2[(long)p * 96 + d2]
           + y1[(long)pT * 96 + d2] + y3[(long)pT * 96 + d2];
        s += v1; s2 += v1 * v1;
    }
    #pragma unroll
    for (int m = 32; m >= 1; m >>= 1) {
        s  += __shfl_xor(s,  m, 64);
        s2 += __shfl_xor(s2, m, 64);
    }
    const float mu = s * (1.f / 96.f);
    const float rstd = rsqrtf(s2 * (1.f / 96.f) - mu * mu + 1e-5f);
    out[(long)p * 96 + lane] = (v0 - mu) * rstd * lnw[lane] + lnb[lane];
    if (lane < 32)
        out[(long)p * 96 + 64 + lane] = (v1 - mu) * rstd * lnw[64 + lane] + lnb[64 + lane];
}

extern "C" void kernel_launch(void* const* d_in, const int* in_sizes, int n_in,
                              void* d_out, int out_size, void* d_ws, size_t ws_size,
                              hipStream_t stream) {
    const float* x    = (const float*)d_in[0];
    const float* xpw  = (const float*)d_in[1];
    const float* dtw  = (const float*)d_in[2];
    const float* dtb  = (const float*)d_in[3];
    const float* Alog = (const float*)d_in[4];
    const float* Dsv  = (const float*)d_in[5];
    const float* lnw  = (const float*)d_in[6];
    const float* lnb  = (const float*)d_in[7];
    float* ws = (float*)d_ws;

    float* xpd   = ws + OFF_XPD;
    float* delta = ws + OFF_DELTA;
    float* Bs    = ws + OFF_BS;
    float* Cs    = ws + OFF_CS;
    float* P     = ws + OFF_P;     // -> hin after kC3
    float* S     = ws + OFF_S;
    float* SP    = ws + OFF_SP;
    float* SS    = ws + OFF_SS;
    float* y     = ws + OFF_S;     // aliases S (kD reads only hin = P)
    float* out   = (float*)d_out;

    kT<<<96, 256, 0, stream>>>(x, xpd);
    kA<<<dim3(144, 4), 256, 0, stream>>>(xpd, xpw, dtw, dtb, delta, Bs, Cs);
    kB<<<cK * cCH / 4, 384, 0, stream>>>(xpd, delta, Bs, Alog, P, S);
    kC1<<<288, 256, 0, stream>>>(P, S, SP, SS);
    kC2<<<24, 256, 0, stream>>>(SP, SS);
    kC3<<<288, 256, 0, stream>>>(P, S, SP);
    kD<<<cK * cCH / 4, 384, 0, stream>>>(xpd, delta, Bs, Cs, Alog, Dsv, P, y);
    kE<<<cL / 4, 256, 0, stream>>>(y, lnw, lnb, out);
}